// Round 3
// baseline (331.530 us; speedup 1.0000x reference)
//
#include <hip/hip_runtime.h>
#include <math.h>

#define NB   4
#define H1   1056
#define W1   1920
#define H2   528
#define W2   960
#define NBLK 220    // 11*20 blocks per image, both scales
#define NBW  20
#define NF   36
#define NGAM 9801

__device__ __forceinline__ int reflect_idx(int i, int n) {
    if (i < 0) return -i - 1;
    if (i >= n) return 2 * n - i - 1;
    return i;
}

// ---------------- R_GAM table: R_GAM[i] = exp(2*lgamma(2/g)-lgamma(1/g)-lgamma(3/g)), g=0.2+0.001i
__global__ void k_rgam(float* __restrict__ rg) {
    int i = blockIdx.x * 256 + threadIdx.x;
    if (i < NGAM) {
        float g = (float)i * 0.001f + 0.2f;
        rg[i] = expf(2.0f * lgammaf(2.0f / g) - lgammaf(1.0f / g) - lgammaf(3.0f / g));
    }
}

// ---------------- gray: y = round((.299 r + .587 g + .114 b)*255), cropped to 1056 rows
__global__ void k_gray(const float* __restrict__ x, float* __restrict__ y) {
    int idx = blockIdx.x * 256 + threadIdx.x;
    const int total = NB * H1 * W1;
    if (idx >= total) return;
    int w = idx % W1;
    int t = idx / W1;
    int h = t % H1;
    int b = t / H1;
    size_t base = ((size_t)(b * 3) * 1080 + h) * W1 + w;
    float r  = x[base];
    float g  = x[base + (size_t)1080 * W1];
    float bb = x[base + (size_t)2 * 1080 * W1];
    y[idx] = rintf((0.299f * r + 0.587f * g + 0.114f * bb) * 255.0f);
}

// ---------------- MSCN: separable 7-tap Gaussian (1D weights in f64), replicate pad
// block = (32,8); output tile 32x32; strides chosen for free 2-way LDS banking
__global__ __launch_bounds__(256) void k_mscn(const float* __restrict__ img,
                                              float* __restrict__ out, int H, int W) {
    __shared__ float tile[38][40];   // stride 40: wave(2rowsx32col) -> 2-way (free)
    __shared__ float h1[38][33];     // stride 33: 2-way (free)
    __shared__ float h2[38][33];
    __shared__ float gw1[7];

    int tx = threadIdx.x;            // 0..31
    int ty = threadIdx.y;            // 0..7
    int tid = ty * 32 + tx;

    if (tid < 7) {
        double s = 7.0 / 6.0;
        double sum = 0.0;
        #pragma unroll
        for (int k = 0; k < 7; k++) sum += exp(-(double)((k - 3) * (k - 3)) / (2.0 * s * s));
        double e = exp(-(double)((tid - 3) * (tid - 3)) / (2.0 * s * s));
        gw1[tid] = (float)(e / sum);
    }

    int b = blockIdx.z;
    const float* p = img + (size_t)b * H * W;
    int ox0 = blockIdx.x * 32, oy0 = blockIdx.y * 32;

    for (int t = tid; t < 38 * 38; t += 256) {
        int r = t / 38, c = t % 38;
        int gr = oy0 - 3 + r; gr = gr < 0 ? 0 : (gr >= H ? H - 1 : gr);
        int gc = ox0 - 3 + c; gc = gc < 0 ? 0 : (gc >= W ? W - 1 : gc);
        tile[r][c] = p[(size_t)gr * W + gc];
    }
    __syncthreads();

    // horizontal pass: 38 rows x 32 cols
    for (int t = tid; t < 38 * 32; t += 256) {
        int r = t / 32, c = t % 32;
        float s1 = 0.0f, s2 = 0.0f;
        #pragma unroll
        for (int k = 0; k < 7; k++) {
            float v = tile[r][c + k];
            float w = gw1[k];
            s1 += w * v;
            s2 += w * v * v;
        }
        h1[r][c] = s1;
        h2[r][c] = s2;
    }
    __syncthreads();

    // vertical pass: 4 output rows per thread
    float* q = out + (size_t)b * H * W;
    #pragma unroll
    for (int sy = 0; sy < 4; sy++) {
        int ly = ty + 8 * sy;
        int oy = oy0 + ly, ox = ox0 + tx;
        if (oy < H && ox < W) {
            float s1 = 0.0f, s2 = 0.0f;
            #pragma unroll
            for (int k = 0; k < 7; k++) {
                float w = gw1[k];
                s1 += w * h1[ly + k][tx];
                s2 += w * h2[ly + k][tx];
            }
            float mu  = s1;
            float sig = sqrtf(fabsf(s2 - mu * mu));
            q[(size_t)oy * W + ox] = (tile[ly + 3][tx + 3] - mu) / (sig + 1.0f);
        }
    }
}

// ---------------- bicubic half-resize: fixed 8-tap filter, taps at 2i-3..2i+4, reflect
__device__ const float RW8[8] = {-0.01171875f, -0.03515625f, 0.11328125f, 0.43359375f,
                                  0.43359375f,  0.11328125f, -0.03515625f, -0.01171875f};

__global__ void k_resizeH(const float* __restrict__ y, float* __restrict__ out) {
    int idx = blockIdx.x * 256 + threadIdx.x;
    const int total = NB * H2 * W1;
    if (idx >= total) return;
    int w = idx % W1;
    int t = idx / W1;
    int i = t % H2;
    int b = t / H2;
    const float* p = y + (size_t)b * H1 * W1 + w;
    float acc = 0.0f;
    int base = 2 * i - 3;
    #pragma unroll
    for (int pp = 0; pp < 8; pp++) {
        int r = reflect_idx(base + pp, H1);
        acc += RW8[pp] * (p[(size_t)r * W1] / 255.0f);
    }
    out[idx] = acc;
}

__global__ void k_resizeW(const float* __restrict__ t, float* __restrict__ out) {
    int idx = blockIdx.x * 256 + threadIdx.x;
    const int total = NB * H2 * W2;
    if (idx >= total) return;
    int j = idx % W2;
    int u = idx / W2;
    int i = u % H2;
    int b = u / H2;
    const float* p = t + ((size_t)b * H2 + i) * W1;
    float acc = 0.0f;
    int base = 2 * j - 3;
    #pragma unroll
    for (int pp = 0; pp < 8; pp++) {
        int c = reflect_idx(base + pp, W1);
        acc += RW8[pp] * p[c];
    }
    out[idx] = acc * 255.0f;
}

// ---------------- per-block AGGD features (5 sets: identity + 4 circular-shift products)
template <int BS, int FOFF>
__global__ __launch_bounds__(256) void k_feats(const float* __restrict__ norm,
                                               const float* __restrict__ rgam,
                                               float* __restrict__ feats, int H, int W) {
    __shared__ float x[BS * BS];
    __shared__ float wred[25][4];
    __shared__ float srn[5], sls[5], srs[5];
    __shared__ float wargd[5][4];
    __shared__ int   wargi[5][4];
    __shared__ int   aidx[5];

    int g  = blockIdx.x;          // b*NBLK + r
    int b  = g / NBLK;
    int r  = g % NBLK;
    int bh = r / NBW, bw = r % NBW;
    const float* p = norm + (size_t)b * H * W + (size_t)(bh * BS) * W + (size_t)(bw * BS);
    int tid = threadIdx.x;

    for (int t = tid; t < BS * BS; t += 256) {
        int i = t / BS, j = t % BS;
        x[t] = p[(size_t)i * W + j];
    }
    __syncthreads();

    const int SI[5] = {0, 0, 1, 1, 1};
    const int SJ[5] = {0, 1, 0, 1, -1};
    float sn[5] = {0, 0, 0, 0, 0}, sp[5] = {0, 0, 0, 0, 0};
    float cn[5] = {0, 0, 0, 0, 0}, cp[5] = {0, 0, 0, 0, 0};
    float sa[5] = {0, 0, 0, 0, 0};

    for (int t = tid; t < BS * BS; t += 256) {
        int i = t / BS, j = t % BS;
        float v0 = x[t];
        #pragma unroll
        for (int s = 0; s < 5; s++) {
            float v;
            if (s == 0) v = v0;
            else {
                int ii = i - SI[s]; if (ii < 0) ii += BS;
                int jj = j - SJ[s]; if (jj < 0) jj += BS; if (jj >= BS) jj -= BS;
                v = v0 * x[ii * BS + jj];
            }
            if (v < 0.0f)      { sn[s] += v * v; cn[s] += 1.0f; }
            else if (v > 0.0f) { sp[s] += v * v; cp[s] += 1.0f; }
            sa[s] += fabsf(v);
        }
    }

    int lane = tid & 63, wv = tid >> 6;
    #pragma unroll
    for (int s = 0; s < 5; s++) {
        float vals[5] = {sn[s], sp[s], cn[s], cp[s], sa[s]};
        #pragma unroll
        for (int m = 0; m < 5; m++) {
            float v = vals[m];
            #pragma unroll
            for (int off = 32; off > 0; off >>= 1) v += __shfl_down(v, off, 64);
            if (lane == 0) wred[s * 5 + m][wv] = v;
        }
    }
    __syncthreads();

    if (tid == 0) {
        for (int s = 0; s < 5; s++) {
            float SN = wred[s*5+0][0] + wred[s*5+0][1] + wred[s*5+0][2] + wred[s*5+0][3];
            float SP = wred[s*5+1][0] + wred[s*5+1][1] + wred[s*5+1][2] + wred[s*5+1][3];
            float CN = wred[s*5+2][0] + wred[s*5+2][1] + wred[s*5+2][2] + wred[s*5+2][3];
            float CP = wred[s*5+3][0] + wred[s*5+3][1] + wred[s*5+3][2] + wred[s*5+3][3];
            float SA = wred[s*5+4][0] + wred[s*5+4][1] + wred[s*5+4][2] + wred[s*5+4][3];
            float ls = sqrtf(SN / CN);
            float rs = sqrtf(SP / CP);
            float gh = ls / rs;
            float Nn = (float)(BS * BS);
            float am = SA / Nn;
            float rhat = (am * am) / ((SN + SP) / Nn);
            float g2 = gh * gh;
            float rn = rhat * (g2 * gh + 1.0f) * (gh + 1.0f) / ((g2 + 1.0f) * (g2 + 1.0f));
            srn[s] = rn; sls[s] = ls; srs[s] = rs;
        }
    }
    __syncthreads();

    float bd[5] = {1e30f, 1e30f, 1e30f, 1e30f, 1e30f};
    int   bi[5] = {0, 0, 0, 0, 0};
    for (int idx = tid; idx < NGAM; idx += 256) {
        float rg = rgam[idx];
        #pragma unroll
        for (int s = 0; s < 5; s++) {
            float d = rg - srn[s]; d *= d;
            if (d < bd[s]) { bd[s] = d; bi[s] = idx; }
        }
    }
    // wave-level argmin (ties -> smaller index, matching jnp.argmin first-min)
    #pragma unroll
    for (int s = 0; s < 5; s++) {
        float d = bd[s];
        int   i = bi[s];
        #pragma unroll
        for (int off = 32; off > 0; off >>= 1) {
            float od = __shfl_down(d, off, 64);
            int   oi = __shfl_down(i, off, 64);
            if (od < d || (od == d && oi < i)) { d = od; i = oi; }
        }
        if (lane == 0) { wargd[s][wv] = d; wargi[s][wv] = i; }
    }
    __syncthreads();

    if (tid == 0) {
        float o[18];
        for (int s = 0; s < 5; s++) {
            float d = wargd[s][0]; int ix = wargi[s][0];
            for (int w2 = 1; w2 < 4; w2++) {
                float od = wargd[s][w2]; int oi = wargi[s][w2];
                if (od < d || (od == d && oi < ix)) { d = od; ix = oi; }
            }
            aidx[s] = ix;
        }
        for (int s = 0; s < 5; s++) {
            float a = (float)aidx[s] * 0.001f + 0.2f;
            float ratio = expf(0.5f * (lgammaf(1.0f / a) - lgammaf(3.0f / a)));
            float bl = sls[s] * ratio;
            float br = srs[s] * ratio;
            if (s == 0) { o[0] = a; o[1] = 0.5f * (bl + br); }
            else {
                float mn = (br - bl) * expf(lgammaf(2.0f / a) - lgammaf(1.0f / a));
                int base = 2 + (s - 1) * 4;
                o[base] = a; o[base + 1] = mn; o[base + 2] = bl; o[base + 3] = br;
            }
        }
        float* fp = feats + (size_t)g * NF + FOFF;
        for (int k = 0; k < 18; k++) fp[k] = o[k];
    }
}

// ---------------- per-batch stats: mean, cov, M=(covp+covd)/2, solve M z = diff, q = diff.z
// Phase 1 (256 thr): build M. Phase 2: wave 0 only, wave-synchronous Gauss-Jordan
// (parallel pivot argmax via shfl butterfly; __threadfence_block for LDS ordering).
__global__ __launch_bounds__(256) void k_stats(const float* __restrict__ feats,
                                               const float* __restrict__ mu_pris,
                                               const float* __restrict__ cov_pris,
                                               float* __restrict__ out) {
    __shared__ float  dist[NBLK * NF];
    __shared__ float  mu[NF];
    __shared__ double M[NF][NF + 1];
    __shared__ double facs[NF];
    __shared__ double dd[NF];

    int b = blockIdx.x, tid = threadIdx.x;
    for (int t = tid; t < NBLK * NF; t += 256) dist[t] = feats[(size_t)b * NBLK * NF + t];
    __syncthreads();
    if (tid < NF) {
        float s = 0.0f;
        for (int n = 0; n < NBLK; n++) s += dist[n * NF + tid];
        mu[tid] = s / (float)NBLK;
    }
    __syncthreads();
    for (int t = tid; t < NBLK * NF; t += 256) dist[t] -= mu[t % NF];
    __syncthreads();
    // cov upper triangle only (symmetric): halves LDS traffic
    for (int t = tid; t < NF * NF; t += 256) {
        int f = t / NF, gg = t % NF;
        if (gg < f) continue;
        float s = 0.0f;
        for (int n = 0; n < NBLK; n++) s += dist[n * NF + f] * dist[n * NF + gg];
        float cv = s / (float)(NBLK - 1);
        float m  = (cov_pris[(size_t)b * NF * NF + t] + cv) * 0.5f;
        M[f][gg] = (double)m;
        M[gg][f] = (double)m;
    }
    if (tid < NF) {
        float d = mu_pris[b * NF + tid] - mu[tid];
        dd[tid] = (double)d;
        M[tid][NF] = (double)d;
    }
    __syncthreads();

    if (tid >= 64) return;           // waves 1..3 done; wave 0 solves alone
    int lane = tid;

    for (int k = 0; k < NF; k++) {
        // parallel pivot argmax: lane i holds |M[i][k]| for i in [k,36)
        double a = (lane >= k && lane < NF) ? fabs(M[lane][k]) : -1.0;
        int p = lane;
        #pragma unroll
        for (int off = 32; off > 0; off >>= 1) {
            double oa = __shfl_xor(a, off, 64);
            int    op = __shfl_xor(p, off, 64);
            if (oa > a || (oa == a && op < p)) { a = oa; p = op; }
        }
        if (p != k && lane <= NF) { double tt = M[k][lane]; M[k][lane] = M[p][lane]; M[p][lane] = tt; }
        __threadfence_block();
        double piv = M[k][k];
        if (lane < NF && lane != k) facs[lane] = M[lane][k] / piv;
        __threadfence_block();
        for (int t = lane; t < NF * (NF + 1); t += 64) {
            int i = t / (NF + 1), j = t % (NF + 1);
            if (i != k && j >= k) M[i][j] -= facs[i] * M[k][j];
        }
        __threadfence_block();
    }

    double c = (lane < NF) ? dd[lane] * (M[lane][NF] / M[lane][lane]) : 0.0;
    #pragma unroll
    for (int off = 32; off > 0; off >>= 1) c += __shfl_xor(c, off, 64);
    if (lane == 0) out[b] = (float)sqrt(c);
}

extern "C" void kernel_launch(void* const* d_in, const int* in_sizes, int n_in,
                              void* d_out, int out_size, void* d_ws, size_t ws_size,
                              hipStream_t stream) {
    const float* x        = (const float*)d_in[0];
    const float* mu_pris  = (const float*)d_in[1];
    const float* cov_pris = (const float*)d_in[2];
    float* out = (float*)d_out;
    float* ws  = (float*)d_ws;

    float* y     = ws;                        // NB*H1*W1 = 8,110,080
    float* nrm   = y + (size_t)NB * H1 * W1;  // 8,110,080 (norm1; later tmpH|half|norm2)
    float* rgam  = nrm + (size_t)NB * H1 * W1;// 9801
    float* feats = rgam + NGAM;               // NB*220*36 = 31,680
    float* tmpH  = nrm;                       // NB*H2*W1 = 4,055,040
    float* half  = tmpH + (size_t)NB * H2 * W1;   // NB*H2*W2 = 2,027,520
    float* nrm2  = half + (size_t)NB * H2 * W2;   // 2,027,520

    k_rgam<<<(NGAM + 255) / 256, 256, 0, stream>>>(rgam);
    k_gray<<<(NB * H1 * W1 + 255) / 256, 256, 0, stream>>>(x, y);

    dim3 thr(32, 8);
    k_mscn<<<dim3(W1 / 32, H1 / 32, NB), thr, 0, stream>>>(y, nrm, H1, W1);
    k_feats<96, 0><<<NB * NBLK, 256, 0, stream>>>(nrm, rgam, feats, H1, W1);

    k_resizeH<<<(NB * H2 * W1 + 255) / 256, 256, 0, stream>>>(y, tmpH);
    k_resizeW<<<(NB * H2 * W2 + 255) / 256, 256, 0, stream>>>(tmpH, half);

    k_mscn<<<dim3(W2 / 32, (H2 + 31) / 32, NB), thr, 0, stream>>>(half, nrm2, H2, W2);
    k_feats<48, 18><<<NB * NBLK, 256, 0, stream>>>(nrm2, rgam, feats, H2, W2);

    k_stats<<<NB, 256, 0, stream>>>(feats, mu_pris, cov_pris, out);
}

// Round 4
// 250.252 us; speedup vs baseline: 1.3248x; 1.3248x over previous
//
#include <hip/hip_runtime.h>
#include <math.h>

#define NB   4
#define H1   1056
#define W1   1920
#define H2   528
#define W2   960
#define NBLK 220    // 11*20 blocks per image, both scales
#define NBW  20
#define NF   36
#define NGAM 9801

__device__ __forceinline__ int reflect_idx(int i, int n) {
    if (i < 0) return -i - 1;
    if (i >= n) return 2 * n - i - 1;
    return i;
}

// ---------------- R_GAM table: R_GAM[i] = exp(2*lgamma(2/g)-lgamma(1/g)-lgamma(3/g)), g=0.2+0.001i
__global__ void k_rgam(float* __restrict__ rg) {
    int i = blockIdx.x * 256 + threadIdx.x;
    if (i < NGAM) {
        float g = (float)i * 0.001f + 0.2f;
        rg[i] = expf(2.0f * lgammaf(2.0f / g) - lgammaf(1.0f / g) - lgammaf(3.0f / g));
    }
}

// ---------------- gray: y = round((.299 r + .587 g + .114 b)*255), cropped to 1056 rows
__global__ void k_gray(const float* __restrict__ x, float* __restrict__ y) {
    int idx = blockIdx.x * 256 + threadIdx.x;
    const int total = NB * H1 * W1;
    if (idx >= total) return;
    int w = idx % W1;
    int t = idx / W1;
    int h = t % H1;
    int b = t / H1;
    size_t base = ((size_t)(b * 3) * 1080 + h) * W1 + w;
    float r  = x[base];
    float g  = x[base + (size_t)1080 * W1];
    float bb = x[base + (size_t)2 * 1080 * W1];
    y[idx] = rintf((0.299f * r + 0.587f * g + 0.114f * bb) * 255.0f);
}

// ---------------- MSCN: separable 7-tap Gaussian (1D weights in f64), replicate pad
// block = (32,8); output tile 32x32; strides chosen for free 2-way LDS banking
__global__ __launch_bounds__(256) void k_mscn(const float* __restrict__ img,
                                              float* __restrict__ out, int H, int W) {
    __shared__ float tile[38][40];   // stride 40: wave(2rowsx32col) -> 2-way (free)
    __shared__ float h1[38][33];     // stride 33: 2-way (free)
    __shared__ float h2[38][33];
    __shared__ float gw1[7];

    int tx = threadIdx.x;            // 0..31
    int ty = threadIdx.y;            // 0..7
    int tid = ty * 32 + tx;

    if (tid < 7) {
        double s = 7.0 / 6.0;
        double sum = 0.0;
        #pragma unroll
        for (int k = 0; k < 7; k++) sum += exp(-(double)((k - 3) * (k - 3)) / (2.0 * s * s));
        double e = exp(-(double)((tid - 3) * (tid - 3)) / (2.0 * s * s));
        gw1[tid] = (float)(e / sum);
    }

    int b = blockIdx.z;
    const float* p = img + (size_t)b * H * W;
    int ox0 = blockIdx.x * 32, oy0 = blockIdx.y * 32;

    for (int t = tid; t < 38 * 38; t += 256) {
        int r = t / 38, c = t % 38;
        int gr = oy0 - 3 + r; gr = gr < 0 ? 0 : (gr >= H ? H - 1 : gr);
        int gc = ox0 - 3 + c; gc = gc < 0 ? 0 : (gc >= W ? W - 1 : gc);
        tile[r][c] = p[(size_t)gr * W + gc];
    }
    __syncthreads();

    // horizontal pass: 38 rows x 32 cols
    for (int t = tid; t < 38 * 32; t += 256) {
        int r = t / 32, c = t % 32;
        float s1 = 0.0f, s2 = 0.0f;
        #pragma unroll
        for (int k = 0; k < 7; k++) {
            float v = tile[r][c + k];
            float w = gw1[k];
            s1 += w * v;
            s2 += w * v * v;
        }
        h1[r][c] = s1;
        h2[r][c] = s2;
    }
    __syncthreads();

    // vertical pass: 4 output rows per thread
    float* q = out + (size_t)b * H * W;
    #pragma unroll
    for (int sy = 0; sy < 4; sy++) {
        int ly = ty + 8 * sy;
        int oy = oy0 + ly, ox = ox0 + tx;
        if (oy < H && ox < W) {
            float s1 = 0.0f, s2 = 0.0f;
            #pragma unroll
            for (int k = 0; k < 7; k++) {
                float w = gw1[k];
                s1 += w * h1[ly + k][tx];
                s2 += w * h2[ly + k][tx];
            }
            float mu  = s1;
            float sig = sqrtf(fabsf(s2 - mu * mu));
            q[(size_t)oy * W + ox] = (tile[ly + 3][tx + 3] - mu) / (sig + 1.0f);
        }
    }
}

// ---------------- bicubic half-resize: fixed 8-tap filter, taps at 2i-3..2i+4, reflect
__device__ const float RW8[8] = {-0.01171875f, -0.03515625f, 0.11328125f, 0.43359375f,
                                  0.43359375f,  0.11328125f, -0.03515625f, -0.01171875f};

__global__ void k_resizeH(const float* __restrict__ y, float* __restrict__ out) {
    int idx = blockIdx.x * 256 + threadIdx.x;
    const int total = NB * H2 * W1;
    if (idx >= total) return;
    int w = idx % W1;
    int t = idx / W1;
    int i = t % H2;
    int b = t / H2;
    const float* p = y + (size_t)b * H1 * W1 + w;
    float acc = 0.0f;
    int base = 2 * i - 3;
    #pragma unroll
    for (int pp = 0; pp < 8; pp++) {
        int r = reflect_idx(base + pp, H1);
        acc += RW8[pp] * (p[(size_t)r * W1] / 255.0f);
    }
    out[idx] = acc;
}

__global__ void k_resizeW(const float* __restrict__ t, float* __restrict__ out) {
    int idx = blockIdx.x * 256 + threadIdx.x;
    const int total = NB * H2 * W2;
    if (idx >= total) return;
    int j = idx % W2;
    int u = idx / W2;
    int i = u % H2;
    int b = u / H2;
    const float* p = t + ((size_t)b * H2 + i) * W1;
    float acc = 0.0f;
    int base = 2 * j - 3;
    #pragma unroll
    for (int pp = 0; pp < 8; pp++) {
        int c = reflect_idx(base + pp, W1);
        acc += RW8[pp] * p[c];
    }
    out[idx] = acc * 255.0f;
}

// ---------------- per-block AGGD features (5 sets: identity + 4 circular-shift products)
template <int BS, int FOFF>
__global__ __launch_bounds__(256) void k_feats(const float* __restrict__ norm,
                                               const float* __restrict__ rgam,
                                               float* __restrict__ feats, int H, int W) {
    __shared__ float x[BS * BS];
    __shared__ float wred[25][4];
    __shared__ float srn[5], sls[5], srs[5];
    __shared__ float wargd[5][4];
    __shared__ int   wargi[5][4];
    __shared__ int   aidx[5];

    int g  = blockIdx.x;          // b*NBLK + r
    int b  = g / NBLK;
    int r  = g % NBLK;
    int bh = r / NBW, bw = r % NBW;
    const float* p = norm + (size_t)b * H * W + (size_t)(bh * BS) * W + (size_t)(bw * BS);
    int tid = threadIdx.x;

    for (int t = tid; t < BS * BS; t += 256) {
        int i = t / BS, j = t % BS;
        x[t] = p[(size_t)i * W + j];
    }
    __syncthreads();

    const int SI[5] = {0, 0, 1, 1, 1};
    const int SJ[5] = {0, 1, 0, 1, -1};
    float sn[5] = {0, 0, 0, 0, 0}, sp[5] = {0, 0, 0, 0, 0};
    float cn[5] = {0, 0, 0, 0, 0}, cp[5] = {0, 0, 0, 0, 0};
    float sa[5] = {0, 0, 0, 0, 0};

    for (int t = tid; t < BS * BS; t += 256) {
        int i = t / BS, j = t % BS;
        float v0 = x[t];
        #pragma unroll
        for (int s = 0; s < 5; s++) {
            float v;
            if (s == 0) v = v0;
            else {
                int ii = i - SI[s]; if (ii < 0) ii += BS;
                int jj = j - SJ[s]; if (jj < 0) jj += BS; if (jj >= BS) jj -= BS;
                v = v0 * x[ii * BS + jj];
            }
            if (v < 0.0f)      { sn[s] += v * v; cn[s] += 1.0f; }
            else if (v > 0.0f) { sp[s] += v * v; cp[s] += 1.0f; }
            sa[s] += fabsf(v);
        }
    }

    int lane = tid & 63, wv = tid >> 6;
    #pragma unroll
    for (int s = 0; s < 5; s++) {
        float vals[5] = {sn[s], sp[s], cn[s], cp[s], sa[s]};
        #pragma unroll
        for (int m = 0; m < 5; m++) {
            float v = vals[m];
            #pragma unroll
            for (int off = 32; off > 0; off >>= 1) v += __shfl_down(v, off, 64);
            if (lane == 0) wred[s * 5 + m][wv] = v;
        }
    }
    __syncthreads();

    if (tid == 0) {
        for (int s = 0; s < 5; s++) {
            float SN = wred[s*5+0][0] + wred[s*5+0][1] + wred[s*5+0][2] + wred[s*5+0][3];
            float SP = wred[s*5+1][0] + wred[s*5+1][1] + wred[s*5+1][2] + wred[s*5+1][3];
            float CN = wred[s*5+2][0] + wred[s*5+2][1] + wred[s*5+2][2] + wred[s*5+2][3];
            float CP = wred[s*5+3][0] + wred[s*5+3][1] + wred[s*5+3][2] + wred[s*5+3][3];
            float SA = wred[s*5+4][0] + wred[s*5+4][1] + wred[s*5+4][2] + wred[s*5+4][3];
            float ls = sqrtf(SN / CN);
            float rs = sqrtf(SP / CP);
            float gh = ls / rs;
            float Nn = (float)(BS * BS);
            float am = SA / Nn;
            float rhat = (am * am) / ((SN + SP) / Nn);
            float g2 = gh * gh;
            float rn = rhat * (g2 * gh + 1.0f) * (gh + 1.0f) / ((g2 + 1.0f) * (g2 + 1.0f));
            srn[s] = rn; sls[s] = ls; srs[s] = rs;
        }
    }
    __syncthreads();

    float bd[5] = {1e30f, 1e30f, 1e30f, 1e30f, 1e30f};
    int   bi[5] = {0, 0, 0, 0, 0};
    for (int idx = tid; idx < NGAM; idx += 256) {
        float rg = rgam[idx];
        #pragma unroll
        for (int s = 0; s < 5; s++) {
            float d = rg - srn[s]; d *= d;
            if (d < bd[s]) { bd[s] = d; bi[s] = idx; }
        }
    }
    // wave-level argmin (ties -> smaller index, matching jnp.argmin first-min)
    #pragma unroll
    for (int s = 0; s < 5; s++) {
        float d = bd[s];
        int   i = bi[s];
        #pragma unroll
        for (int off = 32; off > 0; off >>= 1) {
            float od = __shfl_down(d, off, 64);
            int   oi = __shfl_down(i, off, 64);
            if (od < d || (od == d && oi < i)) { d = od; i = oi; }
        }
        if (lane == 0) { wargd[s][wv] = d; wargi[s][wv] = i; }
    }
    __syncthreads();

    if (tid == 0) {
        float o[18];
        for (int s = 0; s < 5; s++) {
            float d = wargd[s][0]; int ix = wargi[s][0];
            for (int w2 = 1; w2 < 4; w2++) {
                float od = wargd[s][w2]; int oi = wargi[s][w2];
                if (od < d || (od == d && oi < ix)) { d = od; ix = oi; }
            }
            aidx[s] = ix;
        }
        for (int s = 0; s < 5; s++) {
            float a = (float)aidx[s] * 0.001f + 0.2f;
            float ratio = expf(0.5f * (lgammaf(1.0f / a) - lgammaf(3.0f / a)));
            float bl = sls[s] * ratio;
            float br = srs[s] * ratio;
            if (s == 0) { o[0] = a; o[1] = 0.5f * (bl + br); }
            else {
                float mn = (br - bl) * expf(lgammaf(2.0f / a) - lgammaf(1.0f / a));
                int base = 2 + (s - 1) * 4;
                o[base] = a; o[base + 1] = mn; o[base + 2] = bl; o[base + 3] = br;
            }
        }
        float* fp = feats + (size_t)g * NF + FOFF;
        for (int k = 0; k < 18; k++) fp[k] = o[k];
    }
}

// ---------------- per-batch stats: mean, cov, M=(covp+covd)/2, solve M z = diff, q = diff.z
// M is SPD (cov_pris = A.A^T + 1e-3 I, cov_dist PSD) -> Gauss-Jordan WITHOUT pivoting is
// stable; f32 suffices (cond ~1e3, threshold 1.125 abs). 256-thread barrier structure.
__global__ __launch_bounds__(256) void k_stats(const float* __restrict__ feats,
                                               const float* __restrict__ mu_pris,
                                               const float* __restrict__ cov_pris,
                                               float* __restrict__ out) {
    __shared__ float dist[NBLK * NF];
    __shared__ float mu[NF];
    __shared__ float M[NF][NF + 1];
    __shared__ float facs[NF];
    __shared__ float dd[NF];

    int b = blockIdx.x, tid = threadIdx.x;
    for (int t = tid; t < NBLK * NF; t += 256) dist[t] = feats[(size_t)b * NBLK * NF + t];
    __syncthreads();
    if (tid < NF) {
        float s = 0.0f;
        for (int n = 0; n < NBLK; n++) s += dist[n * NF + tid];
        mu[tid] = s / (float)NBLK;
    }
    __syncthreads();
    for (int t = tid; t < NBLK * NF; t += 256) dist[t] -= mu[t % NF];
    __syncthreads();
    for (int t = tid; t < NF * NF; t += 256) {
        int f = t / NF, gg = t % NF;
        float s = 0.0f;
        for (int n = 0; n < NBLK; n++) s += dist[n * NF + f] * dist[n * NF + gg];
        float cv = s / (float)(NBLK - 1);
        M[f][gg] = (cov_pris[(size_t)b * NF * NF + t] + cv) * 0.5f;
    }
    if (tid < NF) {
        float d = mu_pris[b * NF + tid] - mu[tid];
        dd[tid] = d;
        M[tid][NF] = d;
    }
    __syncthreads();

    // no-pivot Gauss-Jordan; update only columns j>k (cols <=k never read again)
    for (int k = 0; k < NF; k++) {
        if (tid < NF && tid != k) facs[tid] = M[tid][k] / M[k][k];
        __syncthreads();
        for (int t = tid; t < NF * (NF + 1); t += 256) {
            int i = t / (NF + 1), j = t % (NF + 1);
            if (i != k && j > k) M[i][j] -= facs[i] * M[k][j];
        }
        __syncthreads();
    }

    // q = sum_i dd[i] * M[i][NF]/M[i][i]; reduce in wave 0 (lanes 36..63 contribute 0)
    if (tid < 64) {
        double c = (tid < NF) ? (double)dd[tid] * ((double)M[tid][NF] / (double)M[tid][tid]) : 0.0;
        #pragma unroll
        for (int off = 32; off > 0; off >>= 1) c += __shfl_down(c, off, 64);
        if (tid == 0) out[b] = (float)sqrt(c);
    }
}

extern "C" void kernel_launch(void* const* d_in, const int* in_sizes, int n_in,
                              void* d_out, int out_size, void* d_ws, size_t ws_size,
                              hipStream_t stream) {
    const float* x        = (const float*)d_in[0];
    const float* mu_pris  = (const float*)d_in[1];
    const float* cov_pris = (const float*)d_in[2];
    float* out = (float*)d_out;
    float* ws  = (float*)d_ws;

    float* y     = ws;                        // NB*H1*W1 = 8,110,080
    float* nrm   = y + (size_t)NB * H1 * W1;  // 8,110,080 (norm1; later tmpH|half|norm2)
    float* rgam  = nrm + (size_t)NB * H1 * W1;// 9801
    float* feats = rgam + NGAM;               // NB*220*36 = 31,680
    float* tmpH  = nrm;                       // NB*H2*W1 = 4,055,040
    float* half  = tmpH + (size_t)NB * H2 * W1;   // NB*H2*W2 = 2,027,520
    float* nrm2  = half + (size_t)NB * H2 * W2;   // 2,027,520

    k_rgam<<<(NGAM + 255) / 256, 256, 0, stream>>>(rgam);
    k_gray<<<(NB * H1 * W1 + 255) / 256, 256, 0, stream>>>(x, y);

    dim3 thr(32, 8);
    k_mscn<<<dim3(W1 / 32, H1 / 32, NB), thr, 0, stream>>>(y, nrm, H1, W1);
    k_feats<96, 0><<<NB * NBLK, 256, 0, stream>>>(nrm, rgam, feats, H1, W1);

    k_resizeH<<<(NB * H2 * W1 + 255) / 256, 256, 0, stream>>>(y, tmpH);
    k_resizeW<<<(NB * H2 * W2 + 255) / 256, 256, 0, stream>>>(tmpH, half);

    k_mscn<<<dim3(W2 / 32, (H2 + 31) / 32, NB), thr, 0, stream>>>(half, nrm2, H2, W2);
    k_feats<48, 18><<<NB * NBLK, 256, 0, stream>>>(nrm2, rgam, feats, H2, W2);

    k_stats<<<NB, 256, 0, stream>>>(feats, mu_pris, cov_pris, out);
}

// Round 5
// 222.545 us; speedup vs baseline: 1.4897x; 1.1245x over previous
//
#include <hip/hip_runtime.h>
#include <math.h>

#define NB   4
#define H1   1056
#define W1   1920
#define H2   528
#define W2   960
#define NBLK 220    // 11*20 blocks per image, both scales
#define NBW  20
#define NF   36
#define NGAM 9801

__device__ __forceinline__ int reflect_idx(int i, int n) {
    if (i < 0) return -i - 1;
    if (i >= n) return 2 * n - i - 1;
    return i;
}

// ---------------- tables: R_GAM + ratio(a) + meanfac(a), a = 0.2 + 0.001*i
// ratio/meanfac precomputed here (a is table-quantized) -> zero lgamma in hot kernels,
// bitwise identical to computing them per block.
__global__ void k_rgam(float* __restrict__ rg, float* __restrict__ rt, float* __restrict__ mf) {
    int i = blockIdx.x * 256 + threadIdx.x;
    if (i < NGAM) {
        float g = (float)i * 0.001f + 0.2f;
        float l1 = lgammaf(1.0f / g);
        float l2 = lgammaf(2.0f / g);
        float l3 = lgammaf(3.0f / g);
        rg[i] = expf(2.0f * l2 - l1 - l3);
        rt[i] = expf(0.5f * (l1 - l3));
        mf[i] = expf(l2 - l1);
    }
}

// ---------------- gray: y = round((.299 r + .587 g + .114 b)*255), cropped to 1056 rows
__global__ void k_gray(const float* __restrict__ x, float* __restrict__ y) {
    int idx = blockIdx.x * 256 + threadIdx.x;
    const int total = NB * H1 * W1;
    if (idx >= total) return;
    int w = idx % W1;
    int t = idx / W1;
    int h = t % H1;
    int b = t / H1;
    size_t base = ((size_t)(b * 3) * 1080 + h) * W1 + w;
    float r  = x[base];
    float g  = x[base + (size_t)1080 * W1];
    float bb = x[base + (size_t)2 * 1080 * W1];
    y[idx] = rintf((0.299f * r + 0.587f * g + 0.114f * bb) * 255.0f);
}

// ---------------- MSCN: separable 7-tap Gaussian (1D weights in f64), replicate pad
// block = (32,8); output tile 32x32; strides chosen for free 2-way LDS banking
__global__ __launch_bounds__(256) void k_mscn(const float* __restrict__ img,
                                              float* __restrict__ out, int H, int W) {
    __shared__ float tile[38][40];   // stride 40: wave(2rowsx32col) -> 2-way (free)
    __shared__ float h1[38][33];     // stride 33: 2-way (free)
    __shared__ float h2[38][33];
    __shared__ float gw1[7];

    int tx = threadIdx.x;            // 0..31
    int ty = threadIdx.y;            // 0..7
    int tid = ty * 32 + tx;

    if (tid < 7) {
        double s = 7.0 / 6.0;
        double sum = 0.0;
        #pragma unroll
        for (int k = 0; k < 7; k++) sum += exp(-(double)((k - 3) * (k - 3)) / (2.0 * s * s));
        double e = exp(-(double)((tid - 3) * (tid - 3)) / (2.0 * s * s));
        gw1[tid] = (float)(e / sum);
    }

    int b = blockIdx.z;
    const float* p = img + (size_t)b * H * W;
    int ox0 = blockIdx.x * 32, oy0 = blockIdx.y * 32;

    for (int t = tid; t < 38 * 38; t += 256) {
        int r = t / 38, c = t % 38;
        int gr = oy0 - 3 + r; gr = gr < 0 ? 0 : (gr >= H ? H - 1 : gr);
        int gc = ox0 - 3 + c; gc = gc < 0 ? 0 : (gc >= W ? W - 1 : gc);
        tile[r][c] = p[(size_t)gr * W + gc];
    }
    __syncthreads();

    // horizontal pass: 38 rows x 32 cols
    for (int t = tid; t < 38 * 32; t += 256) {
        int r = t / 32, c = t % 32;
        float s1 = 0.0f, s2 = 0.0f;
        #pragma unroll
        for (int k = 0; k < 7; k++) {
            float v = tile[r][c + k];
            float w = gw1[k];
            s1 += w * v;
            s2 += w * v * v;
        }
        h1[r][c] = s1;
        h2[r][c] = s2;
    }
    __syncthreads();

    // vertical pass: 4 output rows per thread
    float* q = out + (size_t)b * H * W;
    #pragma unroll
    for (int sy = 0; sy < 4; sy++) {
        int ly = ty + 8 * sy;
        int oy = oy0 + ly, ox = ox0 + tx;
        if (oy < H && ox < W) {
            float s1 = 0.0f, s2 = 0.0f;
            #pragma unroll
            for (int k = 0; k < 7; k++) {
                float w = gw1[k];
                s1 += w * h1[ly + k][tx];
                s2 += w * h2[ly + k][tx];
            }
            float mu  = s1;
            float sig = sqrtf(fabsf(s2 - mu * mu));
            q[(size_t)oy * W + ox] = (tile[ly + 3][tx + 3] - mu) / (sig + 1.0f);
        }
    }
}

// ---------------- bicubic half-resize: fixed 8-tap filter, taps at 2i-3..2i+4, reflect
__device__ const float RW8[8] = {-0.01171875f, -0.03515625f, 0.11328125f, 0.43359375f,
                                  0.43359375f,  0.11328125f, -0.03515625f, -0.01171875f};

__global__ void k_resizeH(const float* __restrict__ y, float* __restrict__ out) {
    int idx = blockIdx.x * 256 + threadIdx.x;
    const int total = NB * H2 * W1;
    if (idx >= total) return;
    int w = idx % W1;
    int t = idx / W1;
    int i = t % H2;
    int b = t / H2;
    const float* p = y + (size_t)b * H1 * W1 + w;
    float acc = 0.0f;
    int base = 2 * i - 3;
    #pragma unroll
    for (int pp = 0; pp < 8; pp++) {
        int r = reflect_idx(base + pp, H1);
        acc += RW8[pp] * (p[(size_t)r * W1] / 255.0f);
    }
    out[idx] = acc;
}

__global__ void k_resizeW(const float* __restrict__ t, float* __restrict__ out) {
    int idx = blockIdx.x * 256 + threadIdx.x;
    const int total = NB * H2 * W2;
    if (idx >= total) return;
    int j = idx % W2;
    int u = idx / W2;
    int i = u % H2;
    int b = u / H2;
    const float* p = t + ((size_t)b * H2 + i) * W1;
    float acc = 0.0f;
    int base = 2 * j - 3;
    #pragma unroll
    for (int pp = 0; pp < 8; pp++) {
        int c = reflect_idx(base + pp, W1);
        acc += RW8[pp] * p[c];
    }
    out[idx] = acc * 255.0f;
}

// ---------------- per-block AGGD features (5 sets: identity + 4 circular-shift products)
// NT=512 threads: grid is fixed at 880 blocks (3.4/CU), so occupancy comes from
// waves/block (8). Branch-free accumulation; table-based finalize (no lgamma).
template <int BS, int FOFF, int NT>
__global__ __launch_bounds__(NT) void k_feats(const float* __restrict__ norm,
                                              const float* __restrict__ rgam,
                                              const float* __restrict__ ratio_t,
                                              const float* __restrict__ meanfac_t,
                                              float* __restrict__ feats, int H, int W) {
    constexpr int NW = NT / 64;
    __shared__ float x[BS * BS];
    __shared__ float wred[25][NW];
    __shared__ float sums[25];
    __shared__ float srn[5], sls[5], srs[5];
    __shared__ float wargd[5][NW];
    __shared__ int   wargi[5][NW];

    int g  = blockIdx.x;          // b*NBLK + r
    int b  = g / NBLK;
    int r  = g % NBLK;
    int bh = r / NBW, bw = r % NBW;
    const float* p = norm + (size_t)b * H * W + (size_t)(bh * BS) * W + (size_t)(bw * BS);
    int tid = threadIdx.x;
    int lane = tid & 63, wv = tid >> 6;

    for (int t = tid; t < BS * BS; t += NT) {
        int i = t / BS, j = t - i * BS;
        x[t] = p[(size_t)i * W + j];
    }
    __syncthreads();

    float sn[5] = {0, 0, 0, 0, 0}, sp[5] = {0, 0, 0, 0, 0};
    float cn[5] = {0, 0, 0, 0, 0}, cp[5] = {0, 0, 0, 0, 0};
    float sa[5] = {0, 0, 0, 0, 0};

    for (int e = tid; e < BS * BS; e += NT) {
        int i  = e / BS, j = e - i * BS;
        int r0 = i * BS;
        int rm = (i == 0 ? BS - 1 : i - 1) * BS;
        int jm = (j == 0 ? BS - 1 : j - 1);
        int jp = (j == BS - 1 ? 0 : j + 1);
        float v0 = x[r0 + j];
        float v[5];
        v[0] = v0;
        v[1] = v0 * x[r0 + jm];
        v[2] = v0 * x[rm + j];
        v[3] = v0 * x[rm + jm];
        v[4] = v0 * x[rm + jp];
        #pragma unroll
        for (int s = 0; s < 5; s++) {
            float vv = v[s];
            float vn = fminf(vv, 0.0f);
            float vp = fmaxf(vv, 0.0f);
            sn[s] += vn * vn;
            sp[s] += vp * vp;
            cn[s] += (vv < 0.0f) ? 1.0f : 0.0f;
            cp[s] += (vv > 0.0f) ? 1.0f : 0.0f;
            sa[s] += fabsf(vv);
        }
    }

    #pragma unroll
    for (int s = 0; s < 5; s++) {
        float vals[5] = {sn[s], sp[s], cn[s], cp[s], sa[s]};
        #pragma unroll
        for (int m = 0; m < 5; m++) {
            float v = vals[m];
            #pragma unroll
            for (int off = 32; off > 0; off >>= 1) v += __shfl_down(v, off, 64);
            if (lane == 0) wred[s * 5 + m][wv] = v;
        }
    }
    __syncthreads();

    if (tid < 25) {
        float s = 0.0f;
        #pragma unroll
        for (int w = 0; w < NW; w++) s += wred[tid][w];
        sums[tid] = s;
    }
    __syncthreads();

    if (tid < 5) {
        int s = tid;
        float SN = sums[s * 5 + 0], SP = sums[s * 5 + 1];
        float CN = sums[s * 5 + 2], CP = sums[s * 5 + 3], SA = sums[s * 5 + 4];
        float ls = sqrtf(SN / CN);
        float rs = sqrtf(SP / CP);
        float gh = ls / rs;
        float Nn = (float)(BS * BS);
        float am = SA / Nn;
        float rhat = (am * am) / ((SN + SP) / Nn);
        float g2 = gh * gh;
        float rn = rhat * (g2 * gh + 1.0f) * (gh + 1.0f) / ((g2 + 1.0f) * (g2 + 1.0f));
        srn[s] = rn; sls[s] = ls; srs[s] = rs;
    }
    __syncthreads();

    float bd[5] = {1e30f, 1e30f, 1e30f, 1e30f, 1e30f};
    int   bi[5] = {0, 0, 0, 0, 0};
    float t0 = srn[0], t1 = srn[1], t2 = srn[2], t3 = srn[3], t4 = srn[4];
    for (int idx = tid; idx < NGAM; idx += NT) {
        float rg = rgam[idx];
        float d0 = (rg - t0) * (rg - t0);
        float d1 = (rg - t1) * (rg - t1);
        float d2 = (rg - t2) * (rg - t2);
        float d3 = (rg - t3) * (rg - t3);
        float d4 = (rg - t4) * (rg - t4);
        if (d0 < bd[0]) { bd[0] = d0; bi[0] = idx; }
        if (d1 < bd[1]) { bd[1] = d1; bi[1] = idx; }
        if (d2 < bd[2]) { bd[2] = d2; bi[2] = idx; }
        if (d3 < bd[3]) { bd[3] = d3; bi[3] = idx; }
        if (d4 < bd[4]) { bd[4] = d4; bi[4] = idx; }
    }
    // wave-level argmin (ties -> smaller index, matching jnp.argmin first-min)
    #pragma unroll
    for (int s = 0; s < 5; s++) {
        float d = bd[s];
        int   i = bi[s];
        #pragma unroll
        for (int off = 32; off > 0; off >>= 1) {
            float od = __shfl_down(d, off, 64);
            int   oi = __shfl_down(i, off, 64);
            if (od < d || (od == d && oi < i)) { d = od; i = oi; }
        }
        if (lane == 0) { wargd[s][wv] = d; wargi[s][wv] = i; }
    }
    __syncthreads();

    if (tid < 5) {
        int s = tid;
        float d = wargd[s][0]; int ix = wargi[s][0];
        #pragma unroll
        for (int w = 1; w < NW; w++) {
            float od = wargd[s][w]; int oi = wargi[s][w];
            if (od < d || (od == d && oi < ix)) { d = od; ix = oi; }
        }
        float a = (float)ix * 0.001f + 0.2f;
        float ratio = ratio_t[ix];
        float bl = sls[s] * ratio;
        float br = srs[s] * ratio;
        float* fp = feats + (size_t)g * NF + FOFF;
        if (s == 0) {
            fp[0] = a; fp[1] = 0.5f * (bl + br);
        } else {
            float mn = (br - bl) * meanfac_t[ix];
            int base = 2 + (s - 1) * 4;
            fp[base] = a; fp[base + 1] = mn; fp[base + 2] = bl; fp[base + 3] = br;
        }
    }
}

// ---------------- per-batch stats: mean, cov, M=(covp+covd)/2, solve M z = diff, q = diff.z
// M is SPD (cov_pris = A.A^T + 1e-3 I, cov_dist PSD) -> Gauss-Jordan WITHOUT pivoting is
// stable; f32 suffices (cond ~1e3, threshold 1.125 abs). 256-thread barrier structure.
__global__ __launch_bounds__(256) void k_stats(const float* __restrict__ feats,
                                               const float* __restrict__ mu_pris,
                                               const float* __restrict__ cov_pris,
                                               float* __restrict__ out) {
    __shared__ float dist[NBLK * NF];
    __shared__ float mu[NF];
    __shared__ float M[NF][NF + 1];
    __shared__ float facs[NF];
    __shared__ float dd[NF];

    int b = blockIdx.x, tid = threadIdx.x;
    for (int t = tid; t < NBLK * NF; t += 256) dist[t] = feats[(size_t)b * NBLK * NF + t];
    __syncthreads();
    if (tid < NF) {
        float s = 0.0f;
        for (int n = 0; n < NBLK; n++) s += dist[n * NF + tid];
        mu[tid] = s / (float)NBLK;
    }
    __syncthreads();
    for (int t = tid; t < NBLK * NF; t += 256) dist[t] -= mu[t % NF];
    __syncthreads();
    for (int t = tid; t < NF * NF; t += 256) {
        int f = t / NF, gg = t % NF;
        float s = 0.0f;
        for (int n = 0; n < NBLK; n++) s += dist[n * NF + f] * dist[n * NF + gg];
        float cv = s / (float)(NBLK - 1);
        M[f][gg] = (cov_pris[(size_t)b * NF * NF + t] + cv) * 0.5f;
    }
    if (tid < NF) {
        float d = mu_pris[b * NF + tid] - mu[tid];
        dd[tid] = d;
        M[tid][NF] = d;
    }
    __syncthreads();

    // no-pivot Gauss-Jordan; update only columns j>k (cols <=k never read again)
    for (int k = 0; k < NF; k++) {
        if (tid < NF && tid != k) facs[tid] = M[tid][k] / M[k][k];
        __syncthreads();
        for (int t = tid; t < NF * (NF + 1); t += 256) {
            int i = t / (NF + 1), j = t % (NF + 1);
            if (i != k && j > k) M[i][j] -= facs[i] * M[k][j];
        }
        __syncthreads();
    }

    // q = sum_i dd[i] * M[i][NF]/M[i][i]; reduce in wave 0 (lanes 36..63 contribute 0)
    if (tid < 64) {
        double c = (tid < NF) ? (double)dd[tid] * ((double)M[tid][NF] / (double)M[tid][tid]) : 0.0;
        #pragma unroll
        for (int off = 32; off > 0; off >>= 1) c += __shfl_down(c, off, 64);
        if (tid == 0) out[b] = (float)sqrt(c);
    }
}

extern "C" void kernel_launch(void* const* d_in, const int* in_sizes, int n_in,
                              void* d_out, int out_size, void* d_ws, size_t ws_size,
                              hipStream_t stream) {
    const float* x        = (const float*)d_in[0];
    const float* mu_pris  = (const float*)d_in[1];
    const float* cov_pris = (const float*)d_in[2];
    float* out = (float*)d_out;
    float* ws  = (float*)d_ws;

    float* y     = ws;                        // NB*H1*W1 = 8,110,080
    float* nrm   = y + (size_t)NB * H1 * W1;  // 8,110,080 (norm1; later tmpH|half|norm2)
    float* rgam  = nrm + (size_t)NB * H1 * W1;// 9801
    float* ratio = rgam + NGAM;               // 9801
    float* mfac  = ratio + NGAM;              // 9801
    float* feats = mfac + NGAM;               // NB*220*36 = 31,680
    float* tmpH  = nrm;                       // NB*H2*W1 = 4,055,040
    float* half  = tmpH + (size_t)NB * H2 * W1;   // NB*H2*W2 = 2,027,520
    float* nrm2  = half + (size_t)NB * H2 * W2;   // 2,027,520

    k_rgam<<<(NGAM + 255) / 256, 256, 0, stream>>>(rgam, ratio, mfac);
    k_gray<<<(NB * H1 * W1 + 255) / 256, 256, 0, stream>>>(x, y);

    dim3 thr(32, 8);
    k_mscn<<<dim3(W1 / 32, H1 / 32, NB), thr, 0, stream>>>(y, nrm, H1, W1);
    k_feats<96, 0, 512><<<NB * NBLK, 512, 0, stream>>>(nrm, rgam, ratio, mfac, feats, H1, W1);

    k_resizeH<<<(NB * H2 * W1 + 255) / 256, 256, 0, stream>>>(y, tmpH);
    k_resizeW<<<(NB * H2 * W2 + 255) / 256, 256, 0, stream>>>(tmpH, half);

    k_mscn<<<dim3(W2 / 32, (H2 + 31) / 32, NB), thr, 0, stream>>>(half, nrm2, H2, W2);
    k_feats<48, 18, 512><<<NB * NBLK, 512, 0, stream>>>(nrm2, rgam, ratio, mfac, feats, H2, W2);

    k_stats<<<NB, 256, 0, stream>>>(feats, mu_pris, cov_pris, out);
}

// Round 6
// 216.667 us; speedup vs baseline: 1.5301x; 1.0271x over previous
//
#include <hip/hip_runtime.h>
#include <math.h>

#define NB   4
#define H1   1056
#define W1   1920
#define H2   528
#define W2   960
#define NBLK 220    // 11*20 blocks per image, both scales
#define NBW  20
#define NF   36
#define NGAM 9801

__device__ __forceinline__ int reflect_idx(int i, int n) {
    if (i < 0) return -i - 1;
    if (i >= n) return 2 * n - i - 1;
    return i;
}

// ---------------- tables: R_GAM + ratio(a) + meanfac(a), a = 0.2 + 0.001*i
__global__ void k_rgam(float* __restrict__ rg, float* __restrict__ rt, float* __restrict__ mf) {
    int i = blockIdx.x * 256 + threadIdx.x;
    if (i < NGAM) {
        float g = (float)i * 0.001f + 0.2f;
        float l1 = lgammaf(1.0f / g);
        float l2 = lgammaf(2.0f / g);
        float l3 = lgammaf(3.0f / g);
        rg[i] = expf(2.0f * l2 - l1 - l3);
        rt[i] = expf(0.5f * (l1 - l3));
        mf[i] = expf(l2 - l1);
    }
}

// ---------------- MSCN, register-blocked separable 7-tap; GRAY variant fuses the
// RGB->gray+round pass (reads x, writes y AND nrm). 32x32 output tile, block (32,8).
// h-pass: 4 cols/item via b128 LDS reads; v-pass: 4 rows/thread (register window).
template <bool GRAY>
__global__ __launch_bounds__(256) void k_mscn(const float* __restrict__ src,
                                              float* __restrict__ ygray,
                                              float* __restrict__ out, int H, int W) {
    __shared__ float tile[38][40];   // 16B-aligned rows, 2-way banking in v-pass
    __shared__ float h1s[38][36];    // stride 36: 16B-aligned, 2-way banking
    __shared__ float h2s[38][36];
    __shared__ float gw1[8];

    int tx = threadIdx.x;            // 0..31
    int ty = threadIdx.y;            // 0..7
    int tid = ty * 32 + tx;

    if (tid < 7) {
        double s = 7.0 / 6.0;
        double sum = 0.0;
        #pragma unroll
        for (int k = 0; k < 7; k++) sum += exp(-(double)((k - 3) * (k - 3)) / (2.0 * s * s));
        double e = exp(-(double)((tid - 3) * (tid - 3)) / (2.0 * s * s));
        gw1[tid] = (float)(e / sum);
    }

    int b = blockIdx.z;
    int ox0 = blockIdx.x * 32, oy0 = blockIdx.y * 32;

    for (int t = tid; t < 38 * 38; t += 256) {
        int r = t / 38, c = t % 38;
        int gr = oy0 - 3 + r; gr = gr < 0 ? 0 : (gr >= H ? H - 1 : gr);
        int gc = ox0 - 3 + c; gc = gc < 0 ? 0 : (gc >= W ? W - 1 : gc);
        float v;
        if (GRAY) {
            const float* px = src + (size_t)b * 3 * 1080 * W;
            size_t o = (size_t)gr * W + gc;
            float rr = px[o];
            float gg = px[o + (size_t)1080 * W];
            float bb = px[o + 2 * (size_t)1080 * W];
            v = rintf((0.299f * rr + 0.587f * gg + 0.114f * bb) * 255.0f);
        } else {
            v = src[(size_t)b * H * W + (size_t)gr * W + gc];
        }
        tile[r][c] = v;
    }
    __syncthreads();

    if (GRAY) {   // write the gray image (exact 32x32 interior = image tiling)
        float* yq = ygray + (size_t)b * H * W;
        for (int t = tid; t < 1024; t += 256) {
            int r = t >> 5, c = t & 31;
            yq[(size_t)(oy0 + r) * W + ox0 + c] = tile[r + 3][c + 3];
        }
    }

    // h-pass: 38 rows x 8 groups of 4 cols
    for (int t = tid; t < 38 * 8; t += 256) {
        int r = t / 8, c0 = (t % 8) * 4;
        float4 f0 = *(const float4*)&tile[r][c0];
        float4 f1 = *(const float4*)&tile[r][c0 + 4];
        float2 f2 = *(const float2*)&tile[r][c0 + 8];
        float v[10] = {f0.x, f0.y, f0.z, f0.w, f1.x, f1.y, f1.z, f1.w, f2.x, f2.y};
        float s1[4] = {0, 0, 0, 0}, s2[4] = {0, 0, 0, 0};
        #pragma unroll
        for (int k = 0; k < 7; k++) {
            float w = gw1[k];
            #pragma unroll
            for (int s = 0; s < 4; s++) {
                float vv = v[s + k];
                s1[s] += w * vv;
                s2[s] += w * vv * vv;
            }
        }
        *(float4*)&h1s[r][c0] = make_float4(s1[0], s1[1], s1[2], s1[3]);
        *(float4*)&h2s[r][c0] = make_float4(s2[0], s2[1], s2[2], s2[3]);
    }
    __syncthreads();

    // v-pass: 4 consecutive rows per thread (register window over h1/h2)
    int ly0 = ty * 4;
    float a1[10], a2[10];
    #pragma unroll
    for (int k = 0; k < 10; k++) { a1[k] = h1s[ly0 + k][tx]; a2[k] = h2s[ly0 + k][tx]; }
    float* q = out + (size_t)b * H * W;
    #pragma unroll
    for (int s = 0; s < 4; s++) {
        int oy = oy0 + ly0 + s, ox = ox0 + tx;
        if (oy < H) {
            float m1 = 0.0f, m2 = 0.0f;
            #pragma unroll
            for (int k = 0; k < 7; k++) {
                float w = gw1[k];
                m1 += w * a1[s + k];
                m2 += w * a2[s + k];
            }
            float sig = sqrtf(fabsf(m2 - m1 * m1));
            q[(size_t)oy * W + ox] = (tile[ly0 + s + 3][tx + 3] - m1) / (sig + 1.0f);
        }
    }
}

// ---------------- fused bicubic half-resize (H then W pass, in LDS): y -> half
__device__ const float RW8[8] = {-0.01171875f, -0.03515625f, 0.11328125f, 0.43359375f,
                                  0.43359375f,  0.11328125f, -0.03515625f, -0.01171875f};

__global__ __launch_bounds__(256) void k_resize(const float* __restrict__ y,
                                                float* __restrict__ half) {
    __shared__ float yt[70][72];
    __shared__ float vv[32][72];
    int tid = threadIdx.y * 32 + threadIdx.x;
    int b = blockIdx.z;
    int j0 = blockIdx.x * 32, i0 = blockIdx.y * 32;
    const float* py = y + (size_t)b * H1 * W1;
    int rbase = 2 * i0 - 3, cbase = 2 * j0 - 3;

    for (int t = tid; t < 70 * 70; t += 256) {
        int r = t / 70, c = t % 70;
        int gr = reflect_idx(rbase + r, H1);
        int gc = reflect_idx(cbase + c, W1);
        yt[r][c] = py[(size_t)gr * W1 + gc] / 255.0f;   // same per-tap /255 as 2-pass version
    }
    __syncthreads();

    // vertical (height) pass first, matching reference axis order
    for (int t = tid; t < 32 * 70; t += 256) {
        int i = t / 70, c = t % 70;
        float acc = 0.0f;
        #pragma unroll
        for (int p = 0; p < 8; p++) acc += RW8[p] * yt[2 * i + p][c];
        vv[i][c] = acc;
    }
    __syncthreads();

    float* ph = half + (size_t)b * H2 * W2;
    for (int t = tid; t < 1024; t += 256) {
        int i = t >> 5, j = t & 31;
        int oy = i0 + i, ox = j0 + j;
        if (oy < H2 && ox < W2) {
            float acc = 0.0f;
            #pragma unroll
            for (int p = 0; p < 8; p++) acc += RW8[p] * vv[i][2 * j + p];
            ph[(size_t)oy * W2 + ox] = acc * 255.0f;
        }
    }
}

// ---------------- per-block AGGD features (5 sets: identity + 4 circular-shift products)
template <int BS, int FOFF, int NT>
__global__ __launch_bounds__(NT) void k_feats(const float* __restrict__ norm,
                                              const float* __restrict__ rgam,
                                              const float* __restrict__ ratio_t,
                                              const float* __restrict__ meanfac_t,
                                              float* __restrict__ feats, int H, int W) {
    constexpr int NW = NT / 64;
    __shared__ float x[BS * BS];
    __shared__ float wred[25][NW];
    __shared__ float sums[25];
    __shared__ float srn[5], sls[5], srs[5];
    __shared__ float wargd[5][NW];
    __shared__ int   wargi[5][NW];

    int g  = blockIdx.x;          // b*NBLK + r
    int b  = g / NBLK;
    int r  = g % NBLK;
    int bh = r / NBW, bw = r % NBW;
    const float* p = norm + (size_t)b * H * W + (size_t)(bh * BS) * W + (size_t)(bw * BS);
    int tid = threadIdx.x;
    int lane = tid & 63, wv = tid >> 6;

    for (int t = tid; t < BS * BS; t += NT) {
        int i = t / BS, j = t - i * BS;
        x[t] = p[(size_t)i * W + j];
    }
    __syncthreads();

    float sn[5] = {0, 0, 0, 0, 0}, sp[5] = {0, 0, 0, 0, 0};
    float cn[5] = {0, 0, 0, 0, 0}, cp[5] = {0, 0, 0, 0, 0};
    float sa[5] = {0, 0, 0, 0, 0};

    for (int e = tid; e < BS * BS; e += NT) {
        int i  = e / BS, j = e - i * BS;
        int r0 = i * BS;
        int rm = (i == 0 ? BS - 1 : i - 1) * BS;
        int jm = (j == 0 ? BS - 1 : j - 1);
        int jp = (j == BS - 1 ? 0 : j + 1);
        float v0 = x[r0 + j];
        float v[5];
        v[0] = v0;
        v[1] = v0 * x[r0 + jm];
        v[2] = v0 * x[rm + j];
        v[3] = v0 * x[rm + jm];
        v[4] = v0 * x[rm + jp];
        #pragma unroll
        for (int s = 0; s < 5; s++) {
            float vv = v[s];
            float vn = fminf(vv, 0.0f);
            float vp = fmaxf(vv, 0.0f);
            sn[s] += vn * vn;
            sp[s] += vp * vp;
            cn[s] += (vv < 0.0f) ? 1.0f : 0.0f;
            cp[s] += (vv > 0.0f) ? 1.0f : 0.0f;
            sa[s] += fabsf(vv);
        }
    }

    #pragma unroll
    for (int s = 0; s < 5; s++) {
        float vals[5] = {sn[s], sp[s], cn[s], cp[s], sa[s]};
        #pragma unroll
        for (int m = 0; m < 5; m++) {
            float v = vals[m];
            #pragma unroll
            for (int off = 32; off > 0; off >>= 1) v += __shfl_down(v, off, 64);
            if (lane == 0) wred[s * 5 + m][wv] = v;
        }
    }
    __syncthreads();

    if (tid < 25) {
        float s = 0.0f;
        #pragma unroll
        for (int w = 0; w < NW; w++) s += wred[tid][w];
        sums[tid] = s;
    }
    __syncthreads();

    if (tid < 5) {
        int s = tid;
        float SN = sums[s * 5 + 0], SP = sums[s * 5 + 1];
        float CN = sums[s * 5 + 2], CP = sums[s * 5 + 3], SA = sums[s * 5 + 4];
        float ls = sqrtf(SN / CN);
        float rs = sqrtf(SP / CP);
        float gh = ls / rs;
        float Nn = (float)(BS * BS);
        float am = SA / Nn;
        float rhat = (am * am) / ((SN + SP) / Nn);
        float g2 = gh * gh;
        float rn = rhat * (g2 * gh + 1.0f) * (gh + 1.0f) / ((g2 + 1.0f) * (g2 + 1.0f));
        srn[s] = rn; sls[s] = ls; srs[s] = rs;
    }
    __syncthreads();

    float bd[5] = {1e30f, 1e30f, 1e30f, 1e30f, 1e30f};
    int   bi[5] = {0, 0, 0, 0, 0};
    float t0 = srn[0], t1 = srn[1], t2 = srn[2], t3 = srn[3], t4 = srn[4];
    for (int idx = tid; idx < NGAM; idx += NT) {
        float rg = rgam[idx];
        float d0 = (rg - t0) * (rg - t0);
        float d1 = (rg - t1) * (rg - t1);
        float d2 = (rg - t2) * (rg - t2);
        float d3 = (rg - t3) * (rg - t3);
        float d4 = (rg - t4) * (rg - t4);
        if (d0 < bd[0]) { bd[0] = d0; bi[0] = idx; }
        if (d1 < bd[1]) { bd[1] = d1; bi[1] = idx; }
        if (d2 < bd[2]) { bd[2] = d2; bi[2] = idx; }
        if (d3 < bd[3]) { bd[3] = d3; bi[3] = idx; }
        if (d4 < bd[4]) { bd[4] = d4; bi[4] = idx; }
    }
    #pragma unroll
    for (int s = 0; s < 5; s++) {
        float d = bd[s];
        int   i = bi[s];
        #pragma unroll
        for (int off = 32; off > 0; off >>= 1) {
            float od = __shfl_down(d, off, 64);
            int   oi = __shfl_down(i, off, 64);
            if (od < d || (od == d && oi < i)) { d = od; i = oi; }
        }
        if (lane == 0) { wargd[s][wv] = d; wargi[s][wv] = i; }
    }
    __syncthreads();

    if (tid < 5) {
        int s = tid;
        float d = wargd[s][0]; int ix = wargi[s][0];
        #pragma unroll
        for (int w = 1; w < NW; w++) {
            float od = wargd[s][w]; int oi = wargi[s][w];
            if (od < d || (od == d && oi < ix)) { d = od; ix = oi; }
        }
        float a = (float)ix * 0.001f + 0.2f;
        float ratio = ratio_t[ix];
        float bl = sls[s] * ratio;
        float br = srs[s] * ratio;
        float* fp = feats + (size_t)g * NF + FOFF;
        if (s == 0) {
            fp[0] = a; fp[1] = 0.5f * (bl + br);
        } else {
            float mn = (br - bl) * meanfac_t[ix];
            int base = 2 + (s - 1) * 4;
            fp[base] = a; fp[base + 1] = mn; fp[base + 2] = bl; fp[base + 3] = br;
        }
    }
}

// ---------------- per-batch stats: cov via transposed dist + 3x3 register tiles,
// then no-pivot Gauss-Jordan (M is SPD), f32 throughout.
__global__ __launch_bounds__(256) void k_stats(const float* __restrict__ feats,
                                               const float* __restrict__ mu_pris,
                                               const float* __restrict__ cov_pris,
                                               float* __restrict__ out) {
    __shared__ float dist[NBLK * NF];
    __shared__ float distT[NF][228];   // stride 228: 16B-aligned rows, banks spread
    __shared__ float mu[NF];
    __shared__ float M[NF][NF + 1];
    __shared__ float facs[NF];
    __shared__ float dd[NF];

    int b = blockIdx.x, tid = threadIdx.x;
    for (int t = tid; t < NBLK * NF; t += 256) dist[t] = feats[(size_t)b * NBLK * NF + t];
    __syncthreads();
    if (tid < NF) {
        float s = 0.0f;
        for (int n = 0; n < NBLK; n++) s += dist[n * NF + tid];
        mu[tid] = s / (float)NBLK;
    }
    __syncthreads();
    for (int t = tid; t < NF * NBLK; t += 256) {
        int f = t / NBLK, n = t % NBLK;
        distT[f][n] = dist[n * NF + f] - mu[f];
    }
    __syncthreads();

    // cov: 12x12 grid of 3x3 tiles, float4 over n (220 = 55*4)
    if (tid < 144) {
        int f0 = (tid / 12) * 3, g0 = (tid % 12) * 3;
        float acc[3][3] = {{0,0,0},{0,0,0},{0,0,0}};
        for (int n = 0; n < NBLK; n += 4) {
            float4 A[3], B[3];
            #pragma unroll
            for (int i = 0; i < 3; i++) A[i] = *(const float4*)&distT[f0 + i][n];
            #pragma unroll
            for (int j = 0; j < 3; j++) B[j] = *(const float4*)&distT[g0 + j][n];
            #pragma unroll
            for (int i = 0; i < 3; i++)
                #pragma unroll
                for (int j = 0; j < 3; j++)
                    acc[i][j] += A[i].x * B[j].x + A[i].y * B[j].y
                               + A[i].z * B[j].z + A[i].w * B[j].w;
        }
        const float* cp = cov_pris + (size_t)b * NF * NF;
        #pragma unroll
        for (int i = 0; i < 3; i++)
            #pragma unroll
            for (int j = 0; j < 3; j++) {
                int f = f0 + i, gg = g0 + j;
                M[f][gg] = (cp[f * NF + gg] + acc[i][j] / (float)(NBLK - 1)) * 0.5f;
            }
    }
    if (tid < NF) {
        float d = mu_pris[b * NF + tid] - mu[tid];
        dd[tid] = d;
        M[tid][NF] = d;
    }
    __syncthreads();

    // no-pivot Gauss-Jordan; update only columns j>k
    for (int k = 0; k < NF; k++) {
        if (tid < NF && tid != k) facs[tid] = M[tid][k] / M[k][k];
        __syncthreads();
        for (int t = tid; t < NF * (NF + 1); t += 256) {
            int i = t / (NF + 1), j = t % (NF + 1);
            if (i != k && j > k) M[i][j] -= facs[i] * M[k][j];
        }
        __syncthreads();
    }

    if (tid < 64) {
        double c = (tid < NF) ? (double)dd[tid] * ((double)M[tid][NF] / (double)M[tid][tid]) : 0.0;
        #pragma unroll
        for (int off = 32; off > 0; off >>= 1) c += __shfl_down(c, off, 64);
        if (tid == 0) out[b] = (float)sqrt(c);
    }
}

extern "C" void kernel_launch(void* const* d_in, const int* in_sizes, int n_in,
                              void* d_out, int out_size, void* d_ws, size_t ws_size,
                              hipStream_t stream) {
    const float* x        = (const float*)d_in[0];
    const float* mu_pris  = (const float*)d_in[1];
    const float* cov_pris = (const float*)d_in[2];
    float* out = (float*)d_out;
    float* ws  = (float*)d_ws;

    float* y     = ws;                          // NB*H1*W1 = 8,110,080
    float* nrm   = y + (size_t)NB * H1 * W1;    // 8,110,080 (reused: half | nrm2)
    float* rgam  = nrm + (size_t)NB * H1 * W1;  // 9801
    float* ratio = rgam + NGAM;                 // 9801
    float* mfac  = ratio + NGAM;                // 9801
    float* feats = mfac + NGAM;                 // NB*220*36 = 31,680
    float* half  = nrm;                         // NB*H2*W2 = 2,027,520 (after feats96)
    float* nrm2  = half + (size_t)NB * H2 * W2; // 2,027,520

    k_rgam<<<(NGAM + 255) / 256, 256, 0, stream>>>(rgam, ratio, mfac);

    dim3 thr(32, 8);
    k_mscn<true><<<dim3(W1 / 32, H1 / 32, NB), thr, 0, stream>>>(x, y, nrm, H1, W1);
    k_feats<96, 0, 512><<<NB * NBLK, 512, 0, stream>>>(nrm, rgam, ratio, mfac, feats, H1, W1);

    k_resize<<<dim3(W2 / 32, (H2 + 31) / 32, NB), thr, 0, stream>>>(y, half);

    k_mscn<false><<<dim3(W2 / 32, (H2 + 31) / 32, NB), thr, 0, stream>>>(half, nullptr, nrm2, H2, W2);
    k_feats<48, 18, 512><<<NB * NBLK, 512, 0, stream>>>(nrm2, rgam, ratio, mfac, feats, H2, W2);

    k_stats<<<NB, 256, 0, stream>>>(feats, mu_pris, cov_pris, out);
}

// Round 7
// 211.236 us; speedup vs baseline: 1.5695x; 1.0257x over previous
//
#include <hip/hip_runtime.h>
#include <math.h>

#define NB   4
#define H1   1056
#define W1   1920
#define H2   528
#define W2   960
#define NBLK 220    // 11*20 blocks per image, both scales
#define NBW  20
#define NF   36
#define NGAM 9801

__device__ __forceinline__ int reflect_idx(int i, int n) {
    if (i < 0) return -i - 1;
    if (i >= n) return 2 * n - i - 1;
    return i;
}

// ---------------- tables: R_GAM + ratio(a) + meanfac(a), a = 0.2 + 0.001*i
__global__ void k_rgam(float* __restrict__ rg, float* __restrict__ rt, float* __restrict__ mf) {
    int i = blockIdx.x * 256 + threadIdx.x;
    if (i < NGAM) {
        float g = (float)i * 0.001f + 0.2f;
        float l1 = lgammaf(1.0f / g);
        float l2 = lgammaf(2.0f / g);
        float l3 = lgammaf(3.0f / g);
        rg[i] = expf(2.0f * l2 - l1 - l3);
        rt[i] = expf(0.5f * (l1 - l3));
        mf[i] = expf(l2 - l1);
    }
}

// ---------------- gray: pure streaming, float4 (W1%4==0). y = round(dot(rgb)*255)
__global__ void k_gray(const float4* __restrict__ x, float4* __restrict__ y) {
    int idx = blockIdx.x * 256 + threadIdx.x;
    const int W4 = W1 / 4;
    const int total = NB * H1 * W4;
    if (idx >= total) return;
    int w4 = idx % W4;
    int t  = idx / W4;
    int h  = t % H1;
    int b  = t / H1;
    size_t base = ((size_t)(b * 3) * 1080 + h) * W4 + w4;
    float4 r  = x[base];
    float4 g  = x[base + (size_t)1080 * W4];
    float4 bb = x[base + (size_t)2 * 1080 * W4];
    float4 o;
    o.x = rintf((0.299f * r.x + 0.587f * g.x + 0.114f * bb.x) * 255.0f);
    o.y = rintf((0.299f * r.y + 0.587f * g.y + 0.114f * bb.y) * 255.0f);
    o.z = rintf((0.299f * r.z + 0.587f * g.z + 0.114f * bb.z) * 255.0f);
    o.w = rintf((0.299f * r.w + 0.587f * g.w + 0.114f * bb.w) * 255.0f);
    y[idx] = o;
}

// ---------------- MSCN, register-blocked separable 7-tap, single-channel input.
// 32x32 output tile, block (32,8); h-pass 4 cols via b128; v-pass 4 rows/thread.
__global__ __launch_bounds__(256) void k_mscn(const float* __restrict__ src,
                                              float* __restrict__ out, int H, int W) {
    __shared__ float tile[38][40];
    __shared__ float h1s[38][36];
    __shared__ float h2s[38][36];
    __shared__ float gw1[8];

    int tx = threadIdx.x;            // 0..31
    int ty = threadIdx.y;            // 0..7
    int tid = ty * 32 + tx;

    if (tid < 7) {
        double s = 7.0 / 6.0;
        double sum = 0.0;
        #pragma unroll
        for (int k = 0; k < 7; k++) sum += exp(-(double)((k - 3) * (k - 3)) / (2.0 * s * s));
        double e = exp(-(double)((tid - 3) * (tid - 3)) / (2.0 * s * s));
        gw1[tid] = (float)(e / sum);
    }

    int b = blockIdx.z;
    const float* p = src + (size_t)b * H * W;
    int ox0 = blockIdx.x * 32, oy0 = blockIdx.y * 32;

    for (int t = tid; t < 38 * 38; t += 256) {
        int r = t / 38, c = t % 38;
        int gr = oy0 - 3 + r; gr = gr < 0 ? 0 : (gr >= H ? H - 1 : gr);
        int gc = ox0 - 3 + c; gc = gc < 0 ? 0 : (gc >= W ? W - 1 : gc);
        tile[r][c] = p[(size_t)gr * W + gc];
    }
    __syncthreads();

    // h-pass: 38 rows x 8 groups of 4 cols
    for (int t = tid; t < 38 * 8; t += 256) {
        int r = t / 8, c0 = (t % 8) * 4;
        float4 f0 = *(const float4*)&tile[r][c0];
        float4 f1 = *(const float4*)&tile[r][c0 + 4];
        float2 f2 = *(const float2*)&tile[r][c0 + 8];
        float v[10] = {f0.x, f0.y, f0.z, f0.w, f1.x, f1.y, f1.z, f1.w, f2.x, f2.y};
        float s1[4] = {0, 0, 0, 0}, s2[4] = {0, 0, 0, 0};
        #pragma unroll
        for (int k = 0; k < 7; k++) {
            float w = gw1[k];
            #pragma unroll
            for (int s = 0; s < 4; s++) {
                float vv = v[s + k];
                s1[s] += w * vv;
                s2[s] += w * vv * vv;
            }
        }
        *(float4*)&h1s[r][c0] = make_float4(s1[0], s1[1], s1[2], s1[3]);
        *(float4*)&h2s[r][c0] = make_float4(s2[0], s2[1], s2[2], s2[3]);
    }
    __syncthreads();

    // v-pass: 4 consecutive rows per thread (register window)
    int ly0 = ty * 4;
    float a1[10], a2[10];
    #pragma unroll
    for (int k = 0; k < 10; k++) { a1[k] = h1s[ly0 + k][tx]; a2[k] = h2s[ly0 + k][tx]; }
    float* q = out + (size_t)b * H * W;
    #pragma unroll
    for (int s = 0; s < 4; s++) {
        int oy = oy0 + ly0 + s, ox = ox0 + tx;
        if (oy < H) {
            float m1 = 0.0f, m2 = 0.0f;
            #pragma unroll
            for (int k = 0; k < 7; k++) {
                float w = gw1[k];
                m1 += w * a1[s + k];
                m2 += w * a2[s + k];
            }
            float sig = sqrtf(fabsf(m2 - m1 * m1));
            q[(size_t)oy * W + ox] = (tile[ly0 + s + 3][tx + 3] - m1) / (sig + 1.0f);
        }
    }
}

// ---------------- fused bicubic half-resize (H then W pass, in LDS): y -> half
__device__ const float RW8[8] = {-0.01171875f, -0.03515625f, 0.11328125f, 0.43359375f,
                                  0.43359375f,  0.11328125f, -0.03515625f, -0.01171875f};

__global__ __launch_bounds__(256) void k_resize(const float* __restrict__ y,
                                                float* __restrict__ half) {
    __shared__ float yt[70][72];
    __shared__ float vv[32][72];
    int tid = threadIdx.y * 32 + threadIdx.x;
    int b = blockIdx.z;
    int j0 = blockIdx.x * 32, i0 = blockIdx.y * 32;
    const float* py = y + (size_t)b * H1 * W1;
    int rbase = 2 * i0 - 3, cbase = 2 * j0 - 3;

    for (int t = tid; t < 70 * 70; t += 256) {
        int r = t / 70, c = t % 70;
        int gr = reflect_idx(rbase + r, H1);
        int gc = reflect_idx(cbase + c, W1);
        yt[r][c] = py[(size_t)gr * W1 + gc] / 255.0f;
    }
    __syncthreads();

    for (int t = tid; t < 32 * 70; t += 256) {
        int i = t / 70, c = t % 70;
        float acc = 0.0f;
        #pragma unroll
        for (int p = 0; p < 8; p++) acc += RW8[p] * yt[2 * i + p][c];
        vv[i][c] = acc;
    }
    __syncthreads();

    float* ph = half + (size_t)b * H2 * W2;
    for (int t = tid; t < 1024; t += 256) {
        int i = t >> 5, j = t & 31;
        int oy = i0 + i, ox = j0 + j;
        if (oy < H2 && ox < W2) {
            float acc = 0.0f;
            #pragma unroll
            for (int p = 0; p < 8; p++) acc += RW8[p] * vv[i][2 * j + p];
            ph[(size_t)oy * W2 + ox] = acc * 255.0f;
        }
    }
}

// ---------------- per-block AGGD features, register-window inner loop.
// NT=384; each thread owns SPAN consecutive cols of one row; row windows loaded
// once into registers (float4/float2). LDS pitch BS+4 de-banks row starts.
template <int BS, int FOFF, int NT>
__global__ __launch_bounds__(NT) void k_feats(const float* __restrict__ norm,
                                              const float* __restrict__ rgam,
                                              const float* __restrict__ ratio_t,
                                              const float* __restrict__ meanfac_t,
                                              float* __restrict__ feats, int H, int W) {
    constexpr int NW    = NT / 64;
    constexpr int PITCH = BS + 4;
    constexpr int SPAN  = (BS * BS) / NT;   // 24 (BS=96) / 6 (BS=48)
    constexpr int TPR   = BS / SPAN;        // threads per row: 4 / 8
    __shared__ __align__(16) float x[BS * PITCH];
    __shared__ float wred[25][NW];
    __shared__ float sums[25];
    __shared__ float srn[5], sls[5], srs[5];
    __shared__ float wargd[5][NW];
    __shared__ int   wargi[5][NW];

    int g  = blockIdx.x;          // b*NBLK + r
    int b  = g / NBLK;
    int r  = g % NBLK;
    int bh = r / NBW, bw = r % NBW;
    const float* p = norm + (size_t)b * H * W + (size_t)(bh * BS) * W + (size_t)(bw * BS);
    int tid = threadIdx.x;
    int lane = tid & 63, wv = tid >> 6;

    for (int t = tid; t < BS * BS; t += NT) {
        int i = t / BS, j = t - i * BS;
        x[i * PITCH + j] = p[(size_t)i * W + j];
    }
    __syncthreads();

    // per-thread register windows
    int i  = tid / TPR;
    int c0 = (tid % TPR) * SPAN;
    int rowc = i * PITCH;
    int rowm = ((i == 0) ? BS - 1 : i - 1) * PITCH;
    float cv[SPAN], mv[SPAN];
    if constexpr (SPAN % 4 == 0) {
        #pragma unroll
        for (int k = 0; k < SPAN / 4; k++) {
            *(float4*)&cv[4 * k] = *(const float4*)&x[rowc + c0 + 4 * k];
            *(float4*)&mv[4 * k] = *(const float4*)&x[rowm + c0 + 4 * k];
        }
    } else {
        #pragma unroll
        for (int k = 0; k < SPAN / 2; k++) {
            *(float2*)&cv[2 * k] = *(const float2*)&x[rowc + c0 + 2 * k];
            *(float2*)&mv[2 * k] = *(const float2*)&x[rowm + c0 + 2 * k];
        }
    }
    float cprev  = x[rowc + (c0 == 0 ? BS - 1 : c0 - 1)];
    float mleft  = x[rowm + (c0 == 0 ? BS - 1 : c0 - 1)];
    float mright = x[rowm + (c0 + SPAN == BS ? 0 : c0 + SPAN)];

    float sn[5] = {0, 0, 0, 0, 0}, sp[5] = {0, 0, 0, 0, 0};
    float cn[5] = {0, 0, 0, 0, 0}, cp[5] = {0, 0, 0, 0, 0};
    float sa[5] = {0, 0, 0, 0, 0};

    #pragma unroll
    for (int k = 0; k < SPAN; k++) {
        float v0 = cv[k];
        float v[5];
        v[0] = v0;
        v[1] = v0 * (k > 0 ? cv[k - 1] : cprev);
        v[2] = v0 * mv[k];
        v[3] = v0 * (k > 0 ? mv[k - 1] : mleft);
        v[4] = v0 * (k + 1 < SPAN ? mv[k + 1] : mright);
        #pragma unroll
        for (int s = 0; s < 5; s++) {
            float vv = v[s];
            float vn = fminf(vv, 0.0f);
            float vp = fmaxf(vv, 0.0f);
            sn[s] += vn * vn;
            sp[s] += vp * vp;
            cn[s] += (vv < 0.0f) ? 1.0f : 0.0f;
            cp[s] += (vv > 0.0f) ? 1.0f : 0.0f;
            sa[s] += fabsf(vv);
        }
    }

    #pragma unroll
    for (int s = 0; s < 5; s++) {
        float vals[5] = {sn[s], sp[s], cn[s], cp[s], sa[s]};
        #pragma unroll
        for (int m = 0; m < 5; m++) {
            float v = vals[m];
            #pragma unroll
            for (int off = 32; off > 0; off >>= 1) v += __shfl_down(v, off, 64);
            if (lane == 0) wred[s * 5 + m][wv] = v;
        }
    }
    __syncthreads();

    if (tid < 25) {
        float s = 0.0f;
        #pragma unroll
        for (int w = 0; w < NW; w++) s += wred[tid][w];
        sums[tid] = s;
    }
    __syncthreads();

    if (tid < 5) {
        int s = tid;
        float SN = sums[s * 5 + 0], SP = sums[s * 5 + 1];
        float CN = sums[s * 5 + 2], CP = sums[s * 5 + 3], SA = sums[s * 5 + 4];
        float ls = sqrtf(SN / CN);
        float rs = sqrtf(SP / CP);
        float gh = ls / rs;
        float Nn = (float)(BS * BS);
        float am = SA / Nn;
        float rhat = (am * am) / ((SN + SP) / Nn);
        float g2 = gh * gh;
        float rn = rhat * (g2 * gh + 1.0f) * (gh + 1.0f) / ((g2 + 1.0f) * (g2 + 1.0f));
        srn[s] = rn; sls[s] = ls; srs[s] = rs;
    }
    __syncthreads();

    float bd[5] = {1e30f, 1e30f, 1e30f, 1e30f, 1e30f};
    int   bi[5] = {0, 0, 0, 0, 0};
    float t0 = srn[0], t1 = srn[1], t2 = srn[2], t3 = srn[3], t4 = srn[4];
    for (int idx = tid; idx < NGAM; idx += NT) {
        float rg = rgam[idx];
        float d0 = (rg - t0) * (rg - t0);
        float d1 = (rg - t1) * (rg - t1);
        float d2 = (rg - t2) * (rg - t2);
        float d3 = (rg - t3) * (rg - t3);
        float d4 = (rg - t4) * (rg - t4);
        if (d0 < bd[0]) { bd[0] = d0; bi[0] = idx; }
        if (d1 < bd[1]) { bd[1] = d1; bi[1] = idx; }
        if (d2 < bd[2]) { bd[2] = d2; bi[2] = idx; }
        if (d3 < bd[3]) { bd[3] = d3; bi[3] = idx; }
        if (d4 < bd[4]) { bd[4] = d4; bi[4] = idx; }
    }
    #pragma unroll
    for (int s = 0; s < 5; s++) {
        float d = bd[s];
        int   ii = bi[s];
        #pragma unroll
        for (int off = 32; off > 0; off >>= 1) {
            float od = __shfl_down(d, off, 64);
            int   oi = __shfl_down(ii, off, 64);
            if (od < d || (od == d && oi < ii)) { d = od; ii = oi; }
        }
        if (lane == 0) { wargd[s][wv] = d; wargi[s][wv] = ii; }
    }
    __syncthreads();

    if (tid < 5) {
        int s = tid;
        float d = wargd[s][0]; int ix = wargi[s][0];
        #pragma unroll
        for (int w = 1; w < NW; w++) {
            float od = wargd[s][w]; int oi = wargi[s][w];
            if (od < d || (od == d && oi < ix)) { d = od; ix = oi; }
        }
        float a = (float)ix * 0.001f + 0.2f;
        float ratio = ratio_t[ix];
        float bl = sls[s] * ratio;
        float br = srs[s] * ratio;
        float* fp = feats + (size_t)g * NF + FOFF;
        if (s == 0) {
            fp[0] = a; fp[1] = 0.5f * (bl + br);
        } else {
            float mn = (br - bl) * meanfac_t[ix];
            int base = 2 + (s - 1) * 4;
            fp[base] = a; fp[base + 1] = mn; fp[base + 2] = bl; fp[base + 3] = br;
        }
    }
}

// ---------------- per-batch stats: cov via transposed dist + 3x3 register tiles,
// then no-pivot Gauss-Jordan (M is SPD), f32 throughout.
__global__ __launch_bounds__(256) void k_stats(const float* __restrict__ feats,
                                               const float* __restrict__ mu_pris,
                                               const float* __restrict__ cov_pris,
                                               float* __restrict__ out) {
    __shared__ float dist[NBLK * NF];
    __shared__ __align__(16) float distT[NF][228];
    __shared__ float mu[NF];
    __shared__ float M[NF][NF + 1];
    __shared__ float facs[NF];
    __shared__ float dd[NF];

    int b = blockIdx.x, tid = threadIdx.x;
    for (int t = tid; t < NBLK * NF; t += 256) dist[t] = feats[(size_t)b * NBLK * NF + t];
    __syncthreads();
    if (tid < NF) {
        float s = 0.0f;
        for (int n = 0; n < NBLK; n++) s += dist[n * NF + tid];
        mu[tid] = s / (float)NBLK;
    }
    __syncthreads();
    for (int t = tid; t < NF * NBLK; t += 256) {
        int f = t / NBLK, n = t % NBLK;
        distT[f][n] = dist[n * NF + f] - mu[f];
    }
    __syncthreads();

    if (tid < 144) {
        int f0 = (tid / 12) * 3, g0 = (tid % 12) * 3;
        float acc[3][3] = {{0,0,0},{0,0,0},{0,0,0}};
        for (int n = 0; n < NBLK; n += 4) {
            float4 A[3], B[3];
            #pragma unroll
            for (int i = 0; i < 3; i++) A[i] = *(const float4*)&distT[f0 + i][n];
            #pragma unroll
            for (int j = 0; j < 3; j++) B[j] = *(const float4*)&distT[g0 + j][n];
            #pragma unroll
            for (int i = 0; i < 3; i++)
                #pragma unroll
                for (int j = 0; j < 3; j++)
                    acc[i][j] += A[i].x * B[j].x + A[i].y * B[j].y
                               + A[i].z * B[j].z + A[i].w * B[j].w;
        }
        const float* cp = cov_pris + (size_t)b * NF * NF;
        #pragma unroll
        for (int i = 0; i < 3; i++)
            #pragma unroll
            for (int j = 0; j < 3; j++) {
                int f = f0 + i, gg = g0 + j;
                M[f][gg] = (cp[f * NF + gg] + acc[i][j] / (float)(NBLK - 1)) * 0.5f;
            }
    }
    if (tid < NF) {
        float d = mu_pris[b * NF + tid] - mu[tid];
        dd[tid] = d;
        M[tid][NF] = d;
    }
    __syncthreads();

    for (int k = 0; k < NF; k++) {
        if (tid < NF && tid != k) facs[tid] = M[tid][k] / M[k][k];
        __syncthreads();
        for (int t = tid; t < NF * (NF + 1); t += 256) {
            int i = t / (NF + 1), j = t % (NF + 1);
            if (i != k && j > k) M[i][j] -= facs[i] * M[k][j];
        }
        __syncthreads();
    }

    if (tid < 64) {
        double c = (tid < NF) ? (double)dd[tid] * ((double)M[tid][NF] / (double)M[tid][tid]) : 0.0;
        #pragma unroll
        for (int off = 32; off > 0; off >>= 1) c += __shfl_down(c, off, 64);
        if (tid == 0) out[b] = (float)sqrt(c);
    }
}

extern "C" void kernel_launch(void* const* d_in, const int* in_sizes, int n_in,
                              void* d_out, int out_size, void* d_ws, size_t ws_size,
                              hipStream_t stream) {
    const float* x        = (const float*)d_in[0];
    const float* mu_pris  = (const float*)d_in[1];
    const float* cov_pris = (const float*)d_in[2];
    float* out = (float*)d_out;
    float* ws  = (float*)d_ws;

    float* y     = ws;                          // NB*H1*W1 = 8,110,080
    float* nrm   = y + (size_t)NB * H1 * W1;    // 8,110,080 (reused: half | nrm2)
    float* rgam  = nrm + (size_t)NB * H1 * W1;  // 9801
    float* ratio = rgam + NGAM;                 // 9801
    float* mfac  = ratio + NGAM;                // 9801
    float* feats = mfac + NGAM;                 // NB*220*36 = 31,680
    float* half  = nrm;                         // NB*H2*W2 = 2,027,520 (after feats96)
    float* nrm2  = half + (size_t)NB * H2 * W2; // 2,027,520

    k_rgam<<<(NGAM + 255) / 256, 256, 0, stream>>>(rgam, ratio, mfac);
    k_gray<<<(NB * H1 * (W1 / 4) + 255) / 256, 256, 0, stream>>>((const float4*)x, (float4*)y);

    dim3 thr(32, 8);
    k_mscn<<<dim3(W1 / 32, H1 / 32, NB), thr, 0, stream>>>(y, nrm, H1, W1);
    k_feats<96, 0, 384><<<NB * NBLK, 384, 0, stream>>>(nrm, rgam, ratio, mfac, feats, H1, W1);

    k_resize<<<dim3(W2 / 32, (H2 + 31) / 32, NB), thr, 0, stream>>>(y, half);

    k_mscn<<<dim3(W2 / 32, (H2 + 31) / 32, NB), thr, 0, stream>>>(half, nrm2, H2, W2);
    k_feats<48, 18, 384><<<NB * NBLK, 384, 0, stream>>>(nrm2, rgam, ratio, mfac, feats, H2, W2);

    k_stats<<<NB, 256, 0, stream>>>(feats, mu_pris, cov_pris, out);
}